// Round 4
// baseline (49.062 us; speedup 1.0000x reference)
//
#include <hip/hip_runtime.h>
#include <math.h>

// ---------------- D1: zero deg + flags; last block does CE ----------------
__global__ __launch_bounds__(256) void k_init_ce(
        unsigned int* __restrict__ deg, int N,
        double* __restrict__ energy_acc,
        unsigned int* __restrict__ hitCount,
        unsigned int* __restrict__ doneCount,
        const float* __restrict__ logits, const int* __restrict__ labels,
        double* __restrict__ ce_acc, int G, int C) {
    int tid = blockIdx.x * blockDim.x + threadIdx.x;
    int nthreads = gridDim.x * blockDim.x;
    for (int i = tid; i < N; i += nthreads) deg[i] = 0u;
    if (tid == 0) { *energy_acc = 0.0; *hitCount = 0u; *doneCount = 0u; }

    if (blockIdx.x == gridDim.x - 1) {
        __shared__ float sh[128];
        int g = threadIdx.x;
        if (g < 128) {
            float lp = 0.f;
            if (g < G) {
                const float* lg = logits + (size_t)g * C;
                float m = lg[0];
                for (int d = 1; d < C; ++d) m = fmaxf(m, lg[d]);
                float s = 0.f;
                for (int d = 0; d < C; ++d) s += expf(lg[d] - m);
                lp = lg[labels[g]] - m - logf(s);
            }
            sh[g] = lp;
        }
        __syncthreads();
        for (int o = 64; o > 0; o >>= 1) {
            if (threadIdx.x < o) sh[threadIdx.x] += sh[threadIdx.x + o];
            __syncthreads();
        }
        if (threadIdx.x == 0) *ce_acc = -(double)sh[0] / (double)G;
    }
}

// ---------------- D2: degree atomics + hit compaction ----------------------
__global__ __launch_bounds__(256) void k_deg_compact(
        const int* __restrict__ row, const int* __restrict__ col,
        const int* __restrict__ batch, unsigned int* __restrict__ deg,
        unsigned int* __restrict__ hitCount, int2* __restrict__ hits, int E) {
    int e = blockIdx.x * blockDim.x + threadIdx.x;
    if (e >= E) return;
    int r = row[e], c = col[e];
    if (batch[r] == batch[c]) {
        atomicAdd(&deg[r], 1u);
        unsigned int idx = atomicAdd(hitCount, 1u);  // wave-aggregated by compiler
        hits[idx] = make_int2(r, c);
    }
}

// ---------------- D3: energy over hits + last-block finalize ---------------
__global__ __launch_bounds__(256) void k_energy_fin(
        const float* __restrict__ x, const unsigned int* __restrict__ deg,
        const unsigned int* __restrict__ hitCount, const int2* __restrict__ hits,
        double* __restrict__ energy_acc, unsigned int* __restrict__ doneCount,
        const double* __restrict__ ce_acc, const int* __restrict__ batch,
        int N, int D, float* __restrict__ out) {
    const int lane = threadIdx.x & 63;
    const int wv = threadIdx.x >> 6;  // wave index within block (0..3)
    const int wave = (blockIdx.x * blockDim.x + threadIdx.x) >> 6;
    const int nwaves = (gridDim.x * blockDim.x) >> 6;
    const int nH = (int)(*hitCount);

    double wsum = 0.0;
    for (int h = wave; h < nH; h += nwaves) {
        int2 rc = hits[h];
        unsigned int dr = deg[rc.x];
        unsigned int dc = deg[rc.y];
        if (dc == 0u) continue;  // dr >= 1 guaranteed by construction
        const float4 a = ((const float4*)(x + (size_t)rc.x * (size_t)D))[lane];
        const float4 b = ((const float4*)(x + (size_t)rc.y * (size_t)D))[lane];
        float dx = a.x - b.x, dy = a.y - b.y, dz = a.z - b.z, dw = a.w - b.w;
        float ss = dx * dx + dy * dy + dz * dz + dw * dw;
        #pragma unroll
        for (int o = 32; o > 0; o >>= 1) ss += __shfl_xor(ss, o);
        if (lane == 0) {
            float ir = 1.0f / sqrtf((float)dr);
            float ic = 1.0f / sqrtf((float)dc);
            wsum += (double)((ir * ic) * ss);
        }
    }

    // block-level double reduction -> one atomic per block
    __shared__ double sdw[4];
    if (lane == 0) sdw[wv] = wsum;
    __syncthreads();
    if (threadIdx.x == 0) {
        double bsum = sdw[0] + sdw[1] + sdw[2] + sdw[3];
        if (bsum != 0.0) atomicAdd(energy_acc, bsum);
        __threadfence();  // release prior to ticket
        unsigned int done = atomicAdd(doneCount, 1u);
        if (done == gridDim.x - 1) {
            double energy = atomicAdd(energy_acc, 0.0);  // coherent read
            out[0] = (float)(*ce_acc + energy / (double)(batch[N - 1] + 1));
        }
    }
}

extern "C" void kernel_launch(void* const* d_in, const int* in_sizes, int n_in,
                              void* d_out, int out_size, void* d_ws, size_t ws_size,
                              hipStream_t stream) {
    const float* logits = (const float*)d_in[0];
    const int* labels = (const int*)d_in[1];
    const float* x = (const float*)d_in[2];
    const int* edge_index = (const int*)d_in[3];
    const int* batch = (const int*)d_in[4];

    const int C = 10;
    const int G = in_sizes[0] / C;   // 128
    const int E = in_sizes[3] / 2;   // 320000
    const int N = in_sizes[4];       // 100000
    const int D = in_sizes[2] / N;   // 256

    const int* row = edge_index;
    const int* col = edge_index + E;

    // workspace: deg[N] | energy_acc | ce_acc | hitCount | doneCount | hits[E]
    size_t off = 0;
    unsigned int* deg = (unsigned int*)((char*)d_ws + off); off += (size_t)N * 4;
    off = (off + 15) & ~(size_t)15;
    double* energy_acc = (double*)((char*)d_ws + off);      off += 8;
    double* ce_acc     = (double*)((char*)d_ws + off);      off += 8;
    unsigned int* hitCount  = (unsigned int*)((char*)d_ws + off); off += 4;
    unsigned int* doneCount = (unsigned int*)((char*)d_ws + off); off += 4;
    off = (off + 15) & ~(size_t)15;
    int2* hits = (int2*)((char*)d_ws + off);

    float* out = (float*)d_out;

    k_init_ce<<<200, 256, 0, stream>>>(deg, N, energy_acc, hitCount, doneCount,
                                       logits, labels, ce_acc, G, C);

    int k2Blocks = (E + 255) / 256;
    k_deg_compact<<<k2Blocks, 256, 0, stream>>>(row, col, batch, deg,
                                                hitCount, hits, E);

    k_energy_fin<<<640, 256, 0, stream>>>(x, deg, hitCount, hits,
                                          energy_acc, doneCount,
                                          ce_acc, batch, N, D, out);
}

// Round 5
// 39.913 us; speedup vs baseline: 1.2292x; 1.2292x over previous
//
#include <hip/hip_runtime.h>
#include <math.h>

// ---------------- D1: zero deg + flags; last block does CE ----------------
__global__ __launch_bounds__(256) void k_init_ce(
        unsigned int* __restrict__ deg, int N,
        double* __restrict__ energy_acc,
        unsigned int* __restrict__ hitCount,
        const float* __restrict__ logits, const int* __restrict__ labels,
        double* __restrict__ ce_acc, int G, int C) {
    int tid = blockIdx.x * blockDim.x + threadIdx.x;
    int nthreads = gridDim.x * blockDim.x;
    for (int i = tid; i < N; i += nthreads) deg[i] = 0u;
    if (tid == 0) { *energy_acc = 0.0; *hitCount = 0u; }

    if (blockIdx.x == gridDim.x - 1) {
        __shared__ float sh[128];
        int g = threadIdx.x;
        if (g < 128) {
            float lp = 0.f;
            if (g < G) {
                const float* lg = logits + (size_t)g * C;
                float m = lg[0];
                for (int d = 1; d < C; ++d) m = fmaxf(m, lg[d]);
                float s = 0.f;
                for (int d = 0; d < C; ++d) s += expf(lg[d] - m);
                lp = lg[labels[g]] - m - logf(s);
            }
            sh[g] = lp;
        }
        __syncthreads();
        for (int o = 64; o > 0; o >>= 1) {
            if (threadIdx.x < o) sh[threadIdx.x] += sh[threadIdx.x + o];
            __syncthreads();
        }
        if (threadIdx.x == 0) *ce_acc = -(double)sh[0] / (double)G;
    }
}

// ---------------- D2: degree atomics + hit compaction ----------------------
__global__ __launch_bounds__(256) void k_deg_compact(
        const int* __restrict__ row, const int* __restrict__ col,
        const int* __restrict__ batch, unsigned int* __restrict__ deg,
        unsigned int* __restrict__ hitCount, int2* __restrict__ hits, int E) {
    int e = blockIdx.x * blockDim.x + threadIdx.x;
    if (e >= E) return;
    int r = row[e], c = col[e];
    if (batch[r] == batch[c]) {
        atomicAdd(&deg[r], 1u);
        unsigned int idx = atomicAdd(hitCount, 1u);  // wave-aggregated
        hits[idx] = make_int2(r, c);
    }
}

// ---------------- D3: energy over hits (no fence, no finalize) -------------
__global__ __launch_bounds__(256) void k_energy(
        const float* __restrict__ x, const unsigned int* __restrict__ deg,
        const unsigned int* __restrict__ hitCount, const int2* __restrict__ hits,
        double* __restrict__ energy_acc, int D) {
    const int lane = threadIdx.x & 63;
    const int wv = threadIdx.x >> 6;
    const int wave = (blockIdx.x * blockDim.x + threadIdx.x) >> 6;
    const int nwaves = (gridDim.x * blockDim.x) >> 6;
    const int nH = (int)(*hitCount);

    double wsum = 0.0;
    for (int h = wave; h < nH; h += nwaves) {
        int2 rc = hits[h];
        unsigned int dr = deg[rc.x];
        unsigned int dc = deg[rc.y];
        if (dc == 0u) continue;  // dr >= 1 guaranteed by construction
        const float4 a = ((const float4*)(x + (size_t)rc.x * (size_t)D))[lane];
        const float4 b = ((const float4*)(x + (size_t)rc.y * (size_t)D))[lane];
        float dx = a.x - b.x, dy = a.y - b.y, dz = a.z - b.z, dw = a.w - b.w;
        float ss = dx * dx + dy * dy + dz * dz + dw * dw;
        #pragma unroll
        for (int o = 32; o > 0; o >>= 1) ss += __shfl_xor(ss, o);
        if (lane == 0) {
            float ir = 1.0f / sqrtf((float)dr);
            float ic = 1.0f / sqrtf((float)dc);
            wsum += (double)((ir * ic) * ss);
        }
    }

    __shared__ double sdw[4];
    if (lane == 0) sdw[wv] = wsum;
    __syncthreads();
    if (threadIdx.x == 0) {
        double bsum = sdw[0] + sdw[1] + sdw[2] + sdw[3];
        if (bsum != 0.0) atomicAdd(energy_acc, bsum);
    }
}

// ---------------- D4: finalize ---------------------------------------------
__global__ void k_finalize(const double* __restrict__ ce_acc,
                           const double* __restrict__ energy_acc,
                           const int* __restrict__ batch, int N,
                           float* __restrict__ out) {
    if (threadIdx.x == 0 && blockIdx.x == 0) {
        double ng = (double)(batch[N - 1] + 1);
        out[0] = (float)(*ce_acc + *energy_acc / ng);
    }
}

extern "C" void kernel_launch(void* const* d_in, const int* in_sizes, int n_in,
                              void* d_out, int out_size, void* d_ws, size_t ws_size,
                              hipStream_t stream) {
    const float* logits = (const float*)d_in[0];
    const int* labels = (const int*)d_in[1];
    const float* x = (const float*)d_in[2];
    const int* edge_index = (const int*)d_in[3];
    const int* batch = (const int*)d_in[4];

    const int C = 10;
    const int G = in_sizes[0] / C;   // 128
    const int E = in_sizes[3] / 2;   // 320000
    const int N = in_sizes[4];       // 100000
    const int D = in_sizes[2] / N;   // 256

    const int* row = edge_index;
    const int* col = edge_index + E;

    // workspace: deg[N] | energy_acc | ce_acc | hitCount | pad | hits[E]
    size_t off = 0;
    unsigned int* deg = (unsigned int*)((char*)d_ws + off); off += (size_t)N * 4;
    off = (off + 15) & ~(size_t)15;
    double* energy_acc = (double*)((char*)d_ws + off);      off += 8;
    double* ce_acc     = (double*)((char*)d_ws + off);      off += 8;
    unsigned int* hitCount = (unsigned int*)((char*)d_ws + off); off += 16;
    int2* hits = (int2*)((char*)d_ws + off);

    float* out = (float*)d_out;

    k_init_ce<<<200, 256, 0, stream>>>(deg, N, energy_acc, hitCount,
                                       logits, labels, ce_acc, G, C);

    int k2Blocks = (E + 255) / 256;
    k_deg_compact<<<k2Blocks, 256, 0, stream>>>(row, col, batch, deg,
                                                hitCount, hits, E);

    k_energy<<<640, 256, 0, stream>>>(x, deg, hitCount, hits, energy_acc, D);

    k_finalize<<<1, 64, 0, stream>>>(ce_acc, energy_acc, batch, N, out);
}

// Round 6
// 23.678 us; speedup vs baseline: 2.0721x; 1.6857x over previous
//
#include <hip/hip_runtime.h>
#include <math.h>

// ---------------- CE kernel: 1 block, G threads ----------------
__global__ void ce_kernel(const float* __restrict__ logits,
                          const int* __restrict__ labels,
                          double* __restrict__ ce_out, int G, int C) {
    __shared__ float sh[128];
    int g = threadIdx.x;
    float lp = 0.f;
    if (g < G) {
        const float* lg = logits + (size_t)g * C;
        float m = lg[0];
        for (int d = 1; d < C; ++d) m = fmaxf(m, lg[d]);
        float s = 0.f;
        for (int d = 0; d < C; ++d) s += expf(lg[d] - m);
        lp = lg[labels[g]] - m - logf(s);
    }
    sh[threadIdx.x] = lp;
    __syncthreads();
    for (int o = blockDim.x / 2; o > 0; o >>= 1) {
        if (threadIdx.x < o) sh[threadIdx.x] += sh[threadIdx.x + o];
        __syncthreads();
    }
    if (threadIdx.x == 0) *ce_out = -(double)sh[0] / (double)G;
}

// ---------------- degree kernel: thread per edge ----------------
__global__ void deg_kernel(const int* __restrict__ row,
                           const int* __restrict__ col,
                           const int* __restrict__ batch,
                           unsigned int* __restrict__ deg, int E) {
    int e = blockIdx.x * blockDim.x + threadIdx.x;
    if (e >= E) return;
    int r = row[e], c = col[e];
    if (batch[r] == batch[c]) atomicAdd(&deg[r], 1u);
}

// ---------------- energy kernel: wave per 64-edge chunk ----------------
__global__ void energy_kernel(const float* __restrict__ x,
                              const int* __restrict__ row,
                              const int* __restrict__ col,
                              const int* __restrict__ batch,
                              const unsigned int* __restrict__ deg,
                              double* __restrict__ energy_acc,
                              int E, int D4 /* = D/4 = 64 */) {
    int gtid = blockIdx.x * blockDim.x + threadIdx.x;
    int wave = gtid >> 6;
    int lane = threadIdx.x & 63;

    int e = wave * 64 + lane;
    int r = 0, c = 0;
    float norm = 0.f;
    bool hit = false;
    if (e < E) {
        r = row[e];
        c = col[e];
        if (batch[r] == batch[c]) {
            unsigned int dr = deg[r], dc = deg[c];
            if (dr > 0 && dc > 0) {
                float ir = 1.0f / sqrtf((float)dr);
                float ic = 1.0f / sqrtf((float)dc);
                norm = ir * ic;
                hit = true;
            }
        }
    }

    double wsum = 0.0;
    unsigned long long mask = __ballot(hit);
    while (mask) {
        int src = __ffsll((unsigned long long)mask) - 1;
        mask &= mask - 1;
        int rr = __shfl(r, src);
        int cc = __shfl(c, src);
        float nn = __shfl(norm, src);
        // whole wave gathers the two feature rows: lane i takes float4 i
        const float4 a = ((const float4*)(x + (size_t)rr * (size_t)(D4 * 4)))[lane];
        const float4 b = ((const float4*)(x + (size_t)cc * (size_t)(D4 * 4)))[lane];
        float dx = a.x - b.x, dy = a.y - b.y, dz = a.z - b.z, dw = a.w - b.w;
        float ss = dx * dx + dy * dy + dz * dz + dw * dw;
        #pragma unroll
        for (int o = 32; o > 0; o >>= 1) ss += __shfl_xor(ss, o);
        if (lane == 0) wsum += (double)(nn * ss);
    }
    if (lane == 0 && wsum != 0.0) atomicAdd(energy_acc, wsum);
}

// ---------------- finalize ----------------
__global__ void finalize_kernel(const double* __restrict__ ce,
                                const double* __restrict__ energy,
                                const int* __restrict__ batch,
                                int N, float* __restrict__ out) {
    if (threadIdx.x == 0 && blockIdx.x == 0) {
        double num_graphs = (double)(batch[N - 1] + 1);
        out[0] = (float)(*ce + *energy / num_graphs);
    }
}

extern "C" void kernel_launch(void* const* d_in, const int* in_sizes, int n_in,
                              void* d_out, int out_size, void* d_ws, size_t ws_size,
                              hipStream_t stream) {
    const float* logits = (const float*)d_in[0];
    const int* labels = (const int*)d_in[1];
    const float* x = (const float*)d_in[2];
    const int* edge_index = (const int*)d_in[3];
    const int* batch = (const int*)d_in[4];

    const int C = 10;
    const int G = in_sizes[0] / C;            // 128
    const int E = in_sizes[3] / 2;            // 320000
    const int N = in_sizes[4];                // 100000
    const int D = in_sizes[2] / N;            // 256
    const int D4 = D / 4;

    const int* row = edge_index;
    const int* col = edge_index + E;

    // workspace layout
    size_t degBytes = ((size_t)N * 4 + 15) & ~(size_t)15;
    unsigned int* deg = (unsigned int*)d_ws;
    double* energy_acc = (double*)((char*)d_ws + degBytes);
    double* ce_acc = (double*)((char*)d_ws + degBytes + 8);

    hipMemsetAsync(d_ws, 0, degBytes + 16, stream);

    ce_kernel<<<1, 128, 0, stream>>>(logits, labels, ce_acc, G, C);

    int degBlocks = (E + 255) / 256;
    deg_kernel<<<degBlocks, 256, 0, stream>>>(row, col, batch, deg, E);

    int waves = (E + 63) / 64;
    int eBlocks = (waves + 3) / 4;            // 4 waves per 256-thread block
    energy_kernel<<<eBlocks, 256, 0, stream>>>(x, row, col, batch, deg,
                                               energy_acc, E, D4);

    finalize_kernel<<<1, 64, 0, stream>>>(ce_acc, energy_acc, batch, N,
                                          (float*)d_out);
}

// Round 7
// 21.935 us; speedup vs baseline: 2.2367x; 1.0795x over previous
//
#include <hip/hip_runtime.h>
#include <math.h>

// ---------------- deg kernel: thread per edge; block 0 also does CE -------
__global__ void deg_ce_kernel(const int* __restrict__ row,
                              const int* __restrict__ col,
                              const int* __restrict__ batch,
                              unsigned int* __restrict__ deg, int E,
                              const float* __restrict__ logits,
                              const int* __restrict__ labels,
                              double* __restrict__ ce_out, int G, int C) {
    int e = blockIdx.x * blockDim.x + threadIdx.x;
    if (e < E) {
        int r = row[e], c = col[e];
        if (batch[r] == batch[c]) atomicAdd(&deg[r], 1u);
    }
    if (blockIdx.x == 0) {
        __shared__ float sh[128];
        int g = threadIdx.x;
        if (g < 128) {
            float lp = 0.f;
            if (g < G) {
                const float* lg = logits + (size_t)g * C;
                float m = lg[0];
                for (int d = 1; d < C; ++d) m = fmaxf(m, lg[d]);
                float s = 0.f;
                for (int d = 0; d < C; ++d) s += expf(lg[d] - m);
                lp = lg[labels[g]] - m - logf(s);
            }
            sh[g] = lp;
        }
        __syncthreads();
        for (int o = 64; o > 0; o >>= 1) {
            if (threadIdx.x < o) sh[threadIdx.x] += sh[threadIdx.x + o];
            __syncthreads();
        }
        if (threadIdx.x == 0) *ce_out = -(double)sh[0] / (double)G;
    }
}

// ---------------- energy kernel: wave per 64-edge chunk ----------------
__global__ void energy_kernel(const float* __restrict__ x,
                              const int* __restrict__ row,
                              const int* __restrict__ col,
                              const int* __restrict__ batch,
                              const unsigned int* __restrict__ deg,
                              double* __restrict__ energy_acc,
                              int E, int D4 /* = D/4 = 64 */) {
    int gtid = blockIdx.x * blockDim.x + threadIdx.x;
    int wave = gtid >> 6;
    int lane = threadIdx.x & 63;

    int e = wave * 64 + lane;
    int r = 0, c = 0;
    float norm = 0.f;
    bool hit = false;
    if (e < E) {
        r = row[e];
        c = col[e];
        if (batch[r] == batch[c]) {
            unsigned int dr = deg[r], dc = deg[c];
            if (dr > 0 && dc > 0) {
                float ir = 1.0f / sqrtf((float)dr);
                float ic = 1.0f / sqrtf((float)dc);
                norm = ir * ic;
                hit = true;
            }
        }
    }

    double wsum = 0.0;
    unsigned long long mask = __ballot(hit);
    while (mask) {
        int src = __ffsll((unsigned long long)mask) - 1;
        mask &= mask - 1;
        int rr = __shfl(r, src);
        int cc = __shfl(c, src);
        float nn = __shfl(norm, src);
        const float4 a = ((const float4*)(x + (size_t)rr * (size_t)(D4 * 4)))[lane];
        const float4 b = ((const float4*)(x + (size_t)cc * (size_t)(D4 * 4)))[lane];
        float dx = a.x - b.x, dy = a.y - b.y, dz = a.z - b.z, dw = a.w - b.w;
        float ss = dx * dx + dy * dy + dz * dz + dw * dw;
        #pragma unroll
        for (int o = 32; o > 0; o >>= 1) ss += __shfl_xor(ss, o);
        if (lane == 0) wsum += (double)(nn * ss);
    }
    if (lane == 0 && wsum != 0.0) atomicAdd(energy_acc, wsum);
}

// ---------------- finalize ----------------
__global__ void finalize_kernel(const double* __restrict__ ce,
                                const double* __restrict__ energy,
                                const int* __restrict__ batch,
                                int N, float* __restrict__ out) {
    if (threadIdx.x == 0 && blockIdx.x == 0) {
        double num_graphs = (double)(batch[N - 1] + 1);
        out[0] = (float)(*ce + *energy / num_graphs);
    }
}

extern "C" void kernel_launch(void* const* d_in, const int* in_sizes, int n_in,
                              void* d_out, int out_size, void* d_ws, size_t ws_size,
                              hipStream_t stream) {
    const float* logits = (const float*)d_in[0];
    const int* labels = (const int*)d_in[1];
    const float* x = (const float*)d_in[2];
    const int* edge_index = (const int*)d_in[3];
    const int* batch = (const int*)d_in[4];

    const int C = 10;
    const int G = in_sizes[0] / C;            // 128
    const int E = in_sizes[3] / 2;            // 320000
    const int N = in_sizes[4];                // 100000
    const int D = in_sizes[2] / N;            // 256
    const int D4 = D / 4;

    const int* row = edge_index;
    const int* col = edge_index + E;

    // workspace layout
    size_t degBytes = ((size_t)N * 4 + 15) & ~(size_t)15;
    unsigned int* deg = (unsigned int*)d_ws;
    double* energy_acc = (double*)((char*)d_ws + degBytes);
    double* ce_acc = (double*)((char*)d_ws + degBytes + 8);

    hipMemsetAsync(d_ws, 0, degBytes + 16, stream);

    int degBlocks = (E + 255) / 256;
    deg_ce_kernel<<<degBlocks, 256, 0, stream>>>(row, col, batch, deg, E,
                                                 logits, labels, ce_acc, G, C);

    int waves = (E + 63) / 64;
    int eBlocks = (waves + 3) / 4;            // 4 waves per 256-thread block
    energy_kernel<<<eBlocks, 256, 0, stream>>>(x, row, col, batch, deg,
                                               energy_acc, E, D4);

    finalize_kernel<<<1, 64, 0, stream>>>(ce_acc, energy_acc, batch, N,
                                          (float*)d_out);
}